// Round 1
// baseline (6490.800 us; speedup 1.0000x reference)
//
#include <hip/hip_runtime.h>
#include <math.h>

#define NU      256
#define NLAYERS 6
#define NBATCH  32768
#define NDIN    784
#define NDOUT   10

#define BM 128
#define BN 128
#define BK 16

// ---------------------------------------------------------------------------
// In-place Gauss-Jordan inversion with partial (row) pivoting, NR gaussj
// structure. One block of 1024 threads per layer.
// Thread (ct, rt): ct = tid&63 owns cols ct*4..ct*4+3; rt = tid>>6 (== wave id)
// owns rows rt*16..rt*16+15. Working matrix lives in registers a[16][4].
// Row swaps are physical (LDS-staged); the final column unscramble
// (NR: swap cols indxr[l]<->l for l = n-1..0) is applied as a permutation
// at the global write.
// ---------------------------------------------------------------------------
__global__ __launch_bounds__(1024) void invert_kernel(
    const float* __restrict__ B0, float* __restrict__ Minv)
{
    const int layer = blockIdx.x;
    const int tid = threadIdx.x;
    const int ct = tid & 63;
    const int rt = tid >> 6;

    __shared__ __align__(16) float  colv[256];
    __shared__ __align__(16) float4 prow4[64];
    __shared__ __align__(16) float  rowA[256];
    __shared__ __align__(16) float  rowB[256];
    __shared__ int   indxr[256];
    __shared__ int   s_p;
    __shared__ float s_pivinv;
    __shared__ int   srccol[256];
    __shared__ int   invsrc[256];

    float a[16][4];
    const float* Ablk = B0 + (size_t)layer * NU * NU;
#pragma unroll
    for (int i = 0; i < 16; ++i) {
        const float4 v = *(const float4*)(Ablk + (size_t)(rt*16 + i)*NU + ct*4);
        a[i][0] = v.x; a[i][1] = v.y; a[i][2] = v.z; a[i][3] = v.w;
    }

    for (int k = 0; k < 256; ++k) {
        const int ctk = k >> 2, jk = k & 3;
        const int rtk = k >> 4, ik = k & 15;
        __syncthreads();                       // prior elimination done
        // ---- broadcast current column k ----
        if (ct == ctk) {
#pragma unroll
            for (int i = 0; i < 16; ++i) colv[rt*16 + i] = a[i][jk];
        }
        __syncthreads();
        // ---- pivot search over rows k..255 (wave 0) ----
        if (tid < 64) {
            float best = -1.0f; int bi = k;
#pragma unroll
            for (int s = 0; s < 4; ++s) {
                const int i = tid + 64*s;
                const float v = (i >= k) ? fabsf(colv[i]) : -1.0f;
                if (v > best) { best = v; bi = i; }
            }
#pragma unroll
            for (int off = 32; off > 0; off >>= 1) {
                const float ob = __shfl_down(best, off);
                const int   oi = __shfl_down(bi, off);
                if (ob > best) { best = ob; bi = oi; }
            }
            if (tid == 0) {
                s_p = bi;
                s_pivinv = 1.0f / colv[bi];
                const float tsw = colv[k]; colv[k] = colv[bi]; colv[bi] = tsw; // post-swap column
                indxr[k] = bi;
            }
        }
        __syncthreads();
        const int p = s_p;
        const float pivinv = s_pivinv;
        const int rtp = p >> 4, ip = p & 15;
        // ---- stage rows k and p for the physical swap ----
        if (rt == rtk) {
            float4 v; v.x = a[ik][0]; v.y = a[ik][1]; v.z = a[ik][2]; v.w = a[ik][3];
            *(float4*)(rowA + ct*4) = v;
        }
        if (rt == rtp) {
            float4 v; v.x = a[ip][0]; v.y = a[ip][1]; v.z = a[ip][2]; v.w = a[ip][3];
            *(float4*)(rowB + ct*4) = v;
        }
        __syncthreads();
        // ---- complete swap; scale new pivot row; publish scaled row ----
        if (rt == rtp) {
            const float4 v = *(const float4*)(rowA + ct*4);
            a[ip][0] = v.x; a[ip][1] = v.y; a[ip][2] = v.z; a[ip][3] = v.w;
        }
        if (rt == rtk) {
            const float4 v = *(const float4*)(rowB + ct*4);
            float vv0 = v.x*pivinv, vv1 = v.y*pivinv, vv2 = v.z*pivinv, vv3 = v.w*pivinv;
            if (ct == ctk) {                       // diagonal slot gets pivinv (in-place GJ)
                if      (jk == 0) vv0 = pivinv;
                else if (jk == 1) vv1 = pivinv;
                else if (jk == 2) vv2 = pivinv;
                else              vv3 = pivinv;
            }
            a[ik][0] = vv0; a[ik][1] = vv1; a[ik][2] = vv2; a[ik][3] = vv3;
            float4 w; w.x = vv0; w.y = vv1; w.z = vv2; w.w = vv3;
            prow4[ct] = w;
        }
        __syncthreads();
        // ---- rank-1 elimination ----
        const float4 pr = prow4[ct];
        float dum[16];
        const float4* colv4 = (const float4*)colv;
#pragma unroll
        for (int ii = 0; ii < 4; ++ii) {
            const float4 d = colv4[rt*4 + ii];
            dum[ii*4+0] = d.x; dum[ii*4+1] = d.y; dum[ii*4+2] = d.z; dum[ii*4+3] = d.w;
        }
        if (rt == rtk) dum[ik] = 0.0f;             // pivot row: no self-elimination
        if (ct == ctk) {                           // zero column k first (NR: a[ll][icol]=0)
#pragma unroll
            for (int i = 0; i < 16; ++i)
                if (!(rt == rtk && i == ik)) a[i][jk] = 0.0f;
        }
#pragma unroll
        for (int i = 0; i < 16; ++i) {
            const float d = dum[i];
            a[i][0] = fmaf(-d, pr.x, a[i][0]);
            a[i][1] = fmaf(-d, pr.y, a[i][1]);
            a[i][2] = fmaf(-d, pr.z, a[i][2]);
            a[i][3] = fmaf(-d, pr.w, a[i][3]);
        }
    }
    __syncthreads();
    // ---- net column permutation from the reverse swap sequence ----
    if (tid == 0) {
        for (int c = 0; c < 256; ++c) srccol[c] = c;
        for (int l2 = 255; l2 >= 0; --l2) {
            const int r = indxr[l2];
            if (r != l2) { const int t2 = srccol[r]; srccol[r] = srccol[l2]; srccol[l2] = t2; }
        }
    }
    __syncthreads();
    if (tid < 256) invsrc[srccol[tid]] = tid;
    __syncthreads();
    float* Mo = Minv + (size_t)layer * NU * NU;
#pragma unroll
    for (int i = 0; i < 16; ++i) {
#pragma unroll
        for (int j = 0; j < 4; ++j) {
            Mo[(size_t)(rt*16 + i)*NU + invsrc[ct*4 + j]] = a[i][j];
        }
    }
}

// ---------------------------------------------------------------------------
// fp32 tiled GEMM: C(Mx256) = alpha * Aop @ Bop (+bias), optional second
// output C2 = tanh(result). BM=BN=128, BK=16, 256 threads, 8x8 microtile.
// transB: B accessed as B[j*256+k] (i.e. @ B^T with B NxK row-major).
// qv: broadcast-add qv[k] to A elements while staging (fuses V0 + 1 q^T).
// ---------------------------------------------------------------------------
__device__ __forceinline__ void gemm_body(
    const float* __restrict__ A, const float* __restrict__ Bm,
    float* __restrict__ C, float* __restrict__ C2,
    const float* __restrict__ bias, const float* __restrict__ qv,
    const int K, const int transB, const float alpha)
{
    __shared__ __align__(16) float As[BK][BM];
    __shared__ __align__(16) float Bs[BK][BN];
    const int t  = threadIdx.x;
    const int tx = t & 15, ty = t >> 4;
    const int m0 = blockIdx.x * BM;
    const int n0 = blockIdx.y * BN;

    float acc[8][8];
#pragma unroll
    for (int i = 0; i < 8; ++i)
#pragma unroll
        for (int j = 0; j < 8; ++j) acc[i][j] = 0.0f;

    const int am = t >> 1;          // 0..127 : row (or B^T row) index within tile
    const int ak = (t & 1) * 8;     // 0 or 8 : k offset
    const int bk = t >> 4;          // 0..15  : k row for non-transposed B
    const int bn = (t & 15) * 8;    // 0..120

    for (int k0 = 0; k0 < K; k0 += BK) {
        const float* Ap = A + (size_t)(m0 + am)*K + (k0 + ak);
        float4 a0 = *(const float4*)(Ap);
        float4 a1 = *(const float4*)(Ap + 4);
        if (qv) {
            a0.x += qv[k0+ak+0]; a0.y += qv[k0+ak+1]; a0.z += qv[k0+ak+2]; a0.w += qv[k0+ak+3];
            a1.x += qv[k0+ak+4]; a1.y += qv[k0+ak+5]; a1.z += qv[k0+ak+6]; a1.w += qv[k0+ak+7];
        }
        As[ak+0][am] = a0.x; As[ak+1][am] = a0.y; As[ak+2][am] = a0.z; As[ak+3][am] = a0.w;
        As[ak+4][am] = a1.x; As[ak+5][am] = a1.y; As[ak+6][am] = a1.z; As[ak+7][am] = a1.w;
        if (!transB) {
            const float* Bp = Bm + (size_t)(k0 + bk)*NU + (n0 + bn);
            const float4 b0 = *(const float4*)(Bp);
            const float4 b1 = *(const float4*)(Bp + 4);
            *(float4*)(&Bs[bk][bn])   = b0;
            *(float4*)(&Bs[bk][bn+4]) = b1;
        } else {
            const float* Bp = Bm + (size_t)(n0 + am)*NU + (k0 + ak);
            const float4 b0 = *(const float4*)(Bp);
            const float4 b1 = *(const float4*)(Bp + 4);
            Bs[ak+0][am] = b0.x; Bs[ak+1][am] = b0.y; Bs[ak+2][am] = b0.z; Bs[ak+3][am] = b0.w;
            Bs[ak+4][am] = b1.x; Bs[ak+5][am] = b1.y; Bs[ak+6][am] = b1.z; Bs[ak+7][am] = b1.w;
        }
        __syncthreads();
#pragma unroll
        for (int kk = 0; kk < BK; ++kk) {
            float af[8], bf[8];
            *(float4*)(af)   = *(const float4*)(&As[kk][ty*8]);
            *(float4*)(af+4) = *(const float4*)(&As[kk][ty*8+4]);
            *(float4*)(bf)   = *(const float4*)(&Bs[kk][tx*8]);
            *(float4*)(bf+4) = *(const float4*)(&Bs[kk][tx*8+4]);
#pragma unroll
            for (int i = 0; i < 8; ++i)
#pragma unroll
                for (int j = 0; j < 8; ++j)
                    acc[i][j] = fmaf(af[i], bf[j], acc[i][j]);
        }
        __syncthreads();
    }

#pragma unroll
    for (int i = 0; i < 8; ++i) {
        const size_t row = m0 + ty*8 + i;
        float o[8];
#pragma unroll
        for (int j = 0; j < 8; ++j) {
            o[j] = alpha * acc[i][j];
            if (bias) o[j] += bias[n0 + tx*8 + j];
        }
        float* cp = C + row*NU + n0 + tx*8;
        float4 v0; v0.x = o[0]; v0.y = o[1]; v0.z = o[2]; v0.w = o[3];
        float4 v1; v1.x = o[4]; v1.y = o[5]; v1.z = o[6]; v1.w = o[7];
        *(float4*)(cp)   = v0;
        *(float4*)(cp+4) = v1;
        if (C2) {
            float* cp2 = C2 + row*NU + n0 + tx*8;
            float4 w0, w1;
            w0.x = tanhf(o[0]); w0.y = tanhf(o[1]); w0.z = tanhf(o[2]); w0.w = tanhf(o[3]);
            w1.x = tanhf(o[4]); w1.y = tanhf(o[5]); w1.z = tanhf(o[6]); w1.w = tanhf(o[7]);
            *(float4*)(cp2)   = w0;
            *(float4*)(cp2+4) = w1;
        }
    }
}

__global__ __launch_bounds__(256) void in_gemm(
    const float* __restrict__ x, const float* __restrict__ Win,
    const float* __restrict__ bin, float* __restrict__ V0, float* __restrict__ V1)
{
    gemm_body(x, Win, V0, V1, bin, nullptr, NDIN, 0, 1.0f);
}

__global__ __launch_bounds__(256) void gemm_nn_neg(
    const float* __restrict__ Ain, const float* __restrict__ M, float* __restrict__ Cout)
{
    gemm_body(Ain, M, Cout, nullptr, nullptr, nullptr, NU, 0, -1.0f);  // V0' = -V1 @ M
}

__global__ __launch_bounds__(256) void gemm_nt_q(
    const float* __restrict__ Ain, const float* __restrict__ M,
    const float* __restrict__ qv, float* __restrict__ Cout)
{
    gemm_body(Ain, M, Cout, nullptr, nullptr, qv, NU, 1, 1.0f);        // V1' = (V0+q) @ M^T
}

// ---------------------------------------------------------------------------
// out = V0 @ W_out + b_out, N=10. One wave per batch row.
// ---------------------------------------------------------------------------
__global__ __launch_bounds__(256) void out_gemm(
    const float* __restrict__ V0, const float* __restrict__ Wout,
    const float* __restrict__ bout, float* __restrict__ out)
{
    __shared__ float Ws[NU*NDOUT];
    const int t = threadIdx.x;
    for (int i = t; i < NU*NDOUT; i += 256) Ws[i] = Wout[i];
    __syncthreads();
    const int lane = t & 63;
    const int wv = t >> 6;
    const int row = blockIdx.x*4 + wv;
    float acc[NDOUT];
#pragma unroll
    for (int j = 0; j < NDOUT; ++j) acc[j] = 0.0f;
#pragma unroll
    for (int s = 0; s < 4; ++s) {
        const int k = lane + 64*s;
        const float v = V0[(size_t)row*NU + k];
#pragma unroll
        for (int j = 0; j < NDOUT; ++j) acc[j] = fmaf(v, Ws[k*NDOUT + j], acc[j]);
    }
#pragma unroll
    for (int off = 32; off > 0; off >>= 1) {
#pragma unroll
        for (int j = 0; j < NDOUT; ++j) acc[j] += __shfl_down(acc[j], off);
    }
    if (lane == 0) {
#pragma unroll
        for (int j = 0; j < NDOUT; ++j) out[(size_t)row*NDOUT + j] = acc[j] + bout[j];
    }
}

extern "C" void kernel_launch(void* const* d_in, const int* in_sizes, int n_in,
                              void* d_out, int out_size, void* d_ws, size_t ws_size,
                              hipStream_t stream)
{
    const float* x    = (const float*)d_in[0];
    const float* Win  = (const float*)d_in[1];
    const float* bin  = (const float*)d_in[2];
    const float* B0   = (const float*)d_in[3];
    const float* q    = (const float*)d_in[4];
    const float* Wout = (const float*)d_in[5];
    const float* bout = (const float*)d_in[6];
    float* out = (float*)d_out;

    // workspace carve: 6 inverses + 3 ping-pong V buffers (~102 MB total)
    float* Minv = (float*)d_ws;
    float* bufA = Minv + (size_t)NLAYERS*NU*NU;
    float* bufB = bufA + (size_t)NBATCH*NU;
    float* bufC = bufB + (size_t)NBATCH*NU;

    const dim3 ggrid(NBATCH/BM, NU/BN);   // 256 x 2 = 512 blocks

    in_gemm<<<ggrid, 256, 0, stream>>>(x, Win, bin, bufA, bufB);       // V0=H, V1=tanh(H)
    invert_kernel<<<NLAYERS, 1024, 0, stream>>>(B0, Minv);

    float* v0 = bufA; float* v1 = bufB; float* fr = bufC;
    for (int l = 0; l < NLAYERS; ++l) {
        const float* Ml = Minv + (size_t)l*NU*NU;
        const float* ql = q + (size_t)l*NU;
        gemm_nn_neg<<<ggrid, 256, 0, stream>>>(v1, Ml, fr);      // newV0 = -V1 @ M   (into free buf)
        gemm_nt_q <<<ggrid, 256, 0, stream>>>(v0, Ml, ql, v1);   // newV1 = (V0+q) @ M^T (over old V1)
        float* tswap = v0; v0 = fr; fr = tswap;                  // old V0 becomes free
    }
    out_gemm<<<NBATCH/4, 256, 0, stream>>>(v0, Wout, bout, out);
}

// Round 2
// 1812.967 us; speedup vs baseline: 3.5802x; 3.5802x over previous
//
#include <hip/hip_runtime.h>
#include <math.h>

#define NU      256
#define NLAYERS 6
#define NBATCH  32768
#define NDIN    784
#define NDOUT   10

#define BM 128
#define BN 128
#define BK 16

// 16-way static-index dispatch over a wave-uniform row index.
// jk/ik (functions of k) and ip (broadcast via LDS) are wave-uniform, so
// these compile to scalar branches; every arm uses compile-time register
// indices. This keeps a[16][4] in VGPRs (round-1 version used dynamic
// indices -> scratch spill -> 5.3 ms).
#define ROW_CASES(BODY) \
    case 0:  BODY(0);  break; case 1:  BODY(1);  break; \
    case 2:  BODY(2);  break; case 3:  BODY(3);  break; \
    case 4:  BODY(4);  break; case 5:  BODY(5);  break; \
    case 6:  BODY(6);  break; case 7:  BODY(7);  break; \
    case 8:  BODY(8);  break; case 9:  BODY(9);  break; \
    case 10: BODY(10); break; case 11: BODY(11); break; \
    case 12: BODY(12); break; case 13: BODY(13); break; \
    case 14: BODY(14); break; case 15: BODY(15); break;

// ---------------------------------------------------------------------------
// In-place Gauss-Jordan inversion with partial (row) pivoting, NR gaussj
// structure. One block of 1024 threads per layer.
// Thread (ct, rt): ct = tid&63 owns cols ct*4..ct*4+3; rt = tid>>6 (== wave id)
// owns rows rt*16..rt*16+15. Working matrix lives in registers a[16][4],
// accessed ONLY with static indices (see ROW_CASES).
// ---------------------------------------------------------------------------
__global__ __launch_bounds__(1024) void invert_kernel(
    const float* __restrict__ B0, float* __restrict__ Minv)
{
    const int layer = blockIdx.x;
    const int tid = threadIdx.x;
    const int ct = tid & 63;
    const int rt = tid >> 6;

    __shared__ __align__(16) float  colv[256];
    __shared__ __align__(16) float4 prow4[64];
    __shared__ __align__(16) float  rowA[256];
    __shared__ __align__(16) float  rowB[256];
    __shared__ int   indxr[256];
    __shared__ int   s_p;
    __shared__ float s_pivinv;
    __shared__ int   srccol[256];
    __shared__ int   invsrc[256];

    float a[16][4];
    const float* Ablk = B0 + (size_t)layer * NU * NU;
#pragma unroll
    for (int i = 0; i < 16; ++i) {
        const float4 v = *(const float4*)(Ablk + (size_t)(rt*16 + i)*NU + ct*4);
        a[i][0] = v.x; a[i][1] = v.y; a[i][2] = v.z; a[i][3] = v.w;
    }

    for (int k = 0; k < 256; ++k) {
        const int ctk = k >> 2, jk = k & 3;
        const int rtk = k >> 4, ik = k & 15;
        __syncthreads();                       // prior elimination done
        // ---- broadcast current column k (jk uniform -> static index) ----
        if (ct == ctk) {
#define BCAST(J) { _Pragma("unroll") for (int i = 0; i < 16; ++i) colv[rt*16 + i] = a[i][J]; }
            if      (jk == 0) BCAST(0)
            else if (jk == 1) BCAST(1)
            else if (jk == 2) BCAST(2)
            else              BCAST(3)
#undef BCAST
        }
        __syncthreads();
        // ---- pivot search over rows k..255 (wave 0) ----
        if (tid < 64) {
            float best = -1.0f; int bi = k;
#pragma unroll
            for (int s = 0; s < 4; ++s) {
                const int i = tid + 64*s;
                const float v = (i >= k) ? fabsf(colv[i]) : -1.0f;
                if (v > best) { best = v; bi = i; }
            }
#pragma unroll
            for (int off = 32; off > 0; off >>= 1) {
                const float ob = __shfl_down(best, off);
                const int   oi = __shfl_down(bi, off);
                if (ob > best) { best = ob; bi = oi; }
            }
            if (tid == 0) {
                s_p = bi;
                s_pivinv = 1.0f / colv[bi];
                const float tsw = colv[k]; colv[k] = colv[bi]; colv[bi] = tsw; // post-swap column
                indxr[k] = bi;
            }
        }
        __syncthreads();
        const int p = s_p;
        const float pivinv = s_pivinv;
        const int rtp = p >> 4, ip = p & 15;
        // ---- stage rows k and p for the physical swap (static reads) ----
        if (rt == rtk) {
            float r0, r1, r2, r3;
#define RD(I) { r0 = a[I][0]; r1 = a[I][1]; r2 = a[I][2]; r3 = a[I][3]; }
            switch (ik) { ROW_CASES(RD) }
#undef RD
            float4 v; v.x = r0; v.y = r1; v.z = r2; v.w = r3;
            *(float4*)(rowA + ct*4) = v;
        }
        if (rt == rtp) {
            float r0, r1, r2, r3;
#define RD(I) { r0 = a[I][0]; r1 = a[I][1]; r2 = a[I][2]; r3 = a[I][3]; }
            switch (ip) { ROW_CASES(RD) }
#undef RD
            float4 v; v.x = r0; v.y = r1; v.z = r2; v.w = r3;
            *(float4*)(rowB + ct*4) = v;
        }
        __syncthreads();
        // ---- complete swap; scale new pivot row; publish scaled row ----
        if (rt == rtp) {
            const float4 v = *(const float4*)(rowA + ct*4);
            const float w0 = v.x, w1 = v.y, w2 = v.z, w3 = v.w;
#define WR(I) { a[I][0] = w0; a[I][1] = w1; a[I][2] = w2; a[I][3] = w3; }
            switch (ip) { ROW_CASES(WR) }
#undef WR
        }
        if (rt == rtk) {
            const float4 v = *(const float4*)(rowB + ct*4);
            float w0 = v.x*pivinv, w1 = v.y*pivinv, w2 = v.z*pivinv, w3 = v.w*pivinv;
            if (ct == ctk) {                       // diagonal slot gets pivinv (in-place GJ)
                if      (jk == 0) w0 = pivinv;
                else if (jk == 1) w1 = pivinv;
                else if (jk == 2) w2 = pivinv;
                else              w3 = pivinv;
            }
#define WR(I) { a[I][0] = w0; a[I][1] = w1; a[I][2] = w2; a[I][3] = w3; }
            switch (ik) { ROW_CASES(WR) }
#undef WR
            float4 w; w.x = w0; w.y = w1; w.z = w2; w.w = w3;
            prow4[ct] = w;
        }
        __syncthreads();
        // ---- rank-1 elimination (all static indices) ----
        const float4 pr = prow4[ct];
        float dum[16];
        const float4* colv4 = (const float4*)colv;
#pragma unroll
        for (int ii = 0; ii < 4; ++ii) {
            const float4 d = colv4[rt*4 + ii];
            dum[ii*4+0] = d.x; dum[ii*4+1] = d.y; dum[ii*4+2] = d.z; dum[ii*4+3] = d.w;
        }
        if (rt == rtk) {                           // pivot row: no self-elimination
#pragma unroll
            for (int i = 0; i < 16; ++i) { if (i == ik) dum[i] = 0.0f; }
        }
        if (ct == ctk) {                           // zero column k first (NR: a[ll][icol]=0)
#define ZCOL(J) { _Pragma("unroll") for (int i = 0; i < 16; ++i) { if (!(rt == rtk && i == ik)) a[i][J] = 0.0f; } }
            if      (jk == 0) ZCOL(0)
            else if (jk == 1) ZCOL(1)
            else if (jk == 2) ZCOL(2)
            else              ZCOL(3)
#undef ZCOL
        }
#pragma unroll
        for (int i = 0; i < 16; ++i) {
            const float d = dum[i];
            a[i][0] = fmaf(-d, pr.x, a[i][0]);
            a[i][1] = fmaf(-d, pr.y, a[i][1]);
            a[i][2] = fmaf(-d, pr.z, a[i][2]);
            a[i][3] = fmaf(-d, pr.w, a[i][3]);
        }
    }
    __syncthreads();
    // ---- net column permutation from the reverse swap sequence ----
    if (tid == 0) {
        for (int c = 0; c < 256; ++c) srccol[c] = c;
        for (int l2 = 255; l2 >= 0; --l2) {
            const int r = indxr[l2];
            if (r != l2) { const int t2 = srccol[r]; srccol[r] = srccol[l2]; srccol[l2] = t2; }
        }
    }
    __syncthreads();
    if (tid < 256) invsrc[srccol[tid]] = tid;
    __syncthreads();
    float* Mo = Minv + (size_t)layer * NU * NU;
#pragma unroll
    for (int i = 0; i < 16; ++i) {
#pragma unroll
        for (int j = 0; j < 4; ++j) {
            Mo[(size_t)(rt*16 + i)*NU + invsrc[ct*4 + j]] = a[i][j];
        }
    }
}

// ---------------------------------------------------------------------------
// fp32 tiled GEMM: C(Mx256) = alpha * Aop @ Bop (+bias), optional second
// output C2 = tanh(result). BM=BN=128, BK=16, 256 threads, 8x8 microtile.
// transB: B accessed as B[j*256+k] (i.e. @ B^T with B NxK row-major).
// qv: broadcast-add qv[k] to A elements while staging (fuses V0 + 1 q^T).
// ---------------------------------------------------------------------------
__device__ __forceinline__ void gemm_body(
    const float* __restrict__ A, const float* __restrict__ Bm,
    float* __restrict__ C, float* __restrict__ C2,
    const float* __restrict__ bias, const float* __restrict__ qv,
    const int K, const int transB, const float alpha)
{
    __shared__ __align__(16) float As[BK][BM];
    __shared__ __align__(16) float Bs[BK][BN];
    const int t  = threadIdx.x;
    const int tx = t & 15, ty = t >> 4;
    const int m0 = blockIdx.x * BM;
    const int n0 = blockIdx.y * BN;

    float acc[8][8];
#pragma unroll
    for (int i = 0; i < 8; ++i)
#pragma unroll
        for (int j = 0; j < 8; ++j) acc[i][j] = 0.0f;

    const int am = t >> 1;          // 0..127 : row (or B^T row) index within tile
    const int ak = (t & 1) * 8;     // 0 or 8 : k offset
    const int bk = t >> 4;          // 0..15  : k row for non-transposed B
    const int bn = (t & 15) * 8;    // 0..120

    for (int k0 = 0; k0 < K; k0 += BK) {
        const float* Ap = A + (size_t)(m0 + am)*K + (k0 + ak);
        float4 a0 = *(const float4*)(Ap);
        float4 a1 = *(const float4*)(Ap + 4);
        if (qv) {
            a0.x += qv[k0+ak+0]; a0.y += qv[k0+ak+1]; a0.z += qv[k0+ak+2]; a0.w += qv[k0+ak+3];
            a1.x += qv[k0+ak+4]; a1.y += qv[k0+ak+5]; a1.z += qv[k0+ak+6]; a1.w += qv[k0+ak+7];
        }
        As[ak+0][am] = a0.x; As[ak+1][am] = a0.y; As[ak+2][am] = a0.z; As[ak+3][am] = a0.w;
        As[ak+4][am] = a1.x; As[ak+5][am] = a1.y; As[ak+6][am] = a1.z; As[ak+7][am] = a1.w;
        if (!transB) {
            const float* Bp = Bm + (size_t)(k0 + bk)*NU + (n0 + bn);
            const float4 b0 = *(const float4*)(Bp);
            const float4 b1 = *(const float4*)(Bp + 4);
            *(float4*)(&Bs[bk][bn])   = b0;
            *(float4*)(&Bs[bk][bn+4]) = b1;
        } else {
            const float* Bp = Bm + (size_t)(n0 + am)*NU + (k0 + ak);
            const float4 b0 = *(const float4*)(Bp);
            const float4 b1 = *(const float4*)(Bp + 4);
            Bs[ak+0][am] = b0.x; Bs[ak+1][am] = b0.y; Bs[ak+2][am] = b0.z; Bs[ak+3][am] = b0.w;
            Bs[ak+4][am] = b1.x; Bs[ak+5][am] = b1.y; Bs[ak+6][am] = b1.z; Bs[ak+7][am] = b1.w;
        }
        __syncthreads();
#pragma unroll
        for (int kk = 0; kk < BK; ++kk) {
            float af[8], bf[8];
            *(float4*)(af)   = *(const float4*)(&As[kk][ty*8]);
            *(float4*)(af+4) = *(const float4*)(&As[kk][ty*8+4]);
            *(float4*)(bf)   = *(const float4*)(&Bs[kk][tx*8]);
            *(float4*)(bf+4) = *(const float4*)(&Bs[kk][tx*8+4]);
#pragma unroll
            for (int i = 0; i < 8; ++i)
#pragma unroll
                for (int j = 0; j < 8; ++j)
                    acc[i][j] = fmaf(af[i], bf[j], acc[i][j]);
        }
        __syncthreads();
    }

#pragma unroll
    for (int i = 0; i < 8; ++i) {
        const size_t row = m0 + ty*8 + i;
        float o[8];
#pragma unroll
        for (int j = 0; j < 8; ++j) {
            o[j] = alpha * acc[i][j];
            if (bias) o[j] += bias[n0 + tx*8 + j];
        }
        float* cp = C + row*NU + n0 + tx*8;
        float4 v0; v0.x = o[0]; v0.y = o[1]; v0.z = o[2]; v0.w = o[3];
        float4 v1; v1.x = o[4]; v1.y = o[5]; v1.z = o[6]; v1.w = o[7];
        *(float4*)(cp)   = v0;
        *(float4*)(cp+4) = v1;
        if (C2) {
            float* cp2 = C2 + row*NU + n0 + tx*8;
            float4 w0, w1;
            w0.x = tanhf(o[0]); w0.y = tanhf(o[1]); w0.z = tanhf(o[2]); w0.w = tanhf(o[3]);
            w1.x = tanhf(o[4]); w1.y = tanhf(o[5]); w1.z = tanhf(o[6]); w1.w = tanhf(o[7]);
            *(float4*)(cp2)   = w0;
            *(float4*)(cp2+4) = w1;
        }
    }
}

__global__ __launch_bounds__(256) void in_gemm(
    const float* __restrict__ x, const float* __restrict__ Win,
    const float* __restrict__ bin, float* __restrict__ V0, float* __restrict__ V1)
{
    gemm_body(x, Win, V0, V1, bin, nullptr, NDIN, 0, 1.0f);
}

__global__ __launch_bounds__(256) void gemm_nn_neg(
    const float* __restrict__ Ain, const float* __restrict__ M, float* __restrict__ Cout)
{
    gemm_body(Ain, M, Cout, nullptr, nullptr, nullptr, NU, 0, -1.0f);  // V0' = -V1 @ M
}

__global__ __launch_bounds__(256) void gemm_nt_q(
    const float* __restrict__ Ain, const float* __restrict__ M,
    const float* __restrict__ qv, float* __restrict__ Cout)
{
    gemm_body(Ain, M, Cout, nullptr, nullptr, qv, NU, 1, 1.0f);        // V1' = (V0+q) @ M^T
}

// ---------------------------------------------------------------------------
// out = V0 @ W_out + b_out, N=10. One wave per batch row.
// ---------------------------------------------------------------------------
__global__ __launch_bounds__(256) void out_gemm(
    const float* __restrict__ V0, const float* __restrict__ Wout,
    const float* __restrict__ bout, float* __restrict__ out)
{
    __shared__ float Ws[NU*NDOUT];
    const int t = threadIdx.x;
    for (int i = t; i < NU*NDOUT; i += 256) Ws[i] = Wout[i];
    __syncthreads();
    const int lane = t & 63;
    const int wv = t >> 6;
    const int row = blockIdx.x*4 + wv;
    float acc[NDOUT];
#pragma unroll
    for (int j = 0; j < NDOUT; ++j) acc[j] = 0.0f;
#pragma unroll
    for (int s = 0; s < 4; ++s) {
        const int k = lane + 64*s;
        const float v = V0[(size_t)row*NU + k];
#pragma unroll
        for (int j = 0; j < NDOUT; ++j) acc[j] = fmaf(v, Ws[k*NDOUT + j], acc[j]);
    }
#pragma unroll
    for (int off = 32; off > 0; off >>= 1) {
#pragma unroll
        for (int j = 0; j < NDOUT; ++j) acc[j] += __shfl_down(acc[j], off);
    }
    if (lane == 0) {
#pragma unroll
        for (int j = 0; j < NDOUT; ++j) out[(size_t)row*NDOUT + j] = acc[j] + bout[j];
    }
}

extern "C" void kernel_launch(void* const* d_in, const int* in_sizes, int n_in,
                              void* d_out, int out_size, void* d_ws, size_t ws_size,
                              hipStream_t stream)
{
    const float* x    = (const float*)d_in[0];
    const float* Win  = (const float*)d_in[1];
    const float* bin  = (const float*)d_in[2];
    const float* B0   = (const float*)d_in[3];
    const float* q    = (const float*)d_in[4];
    const float* Wout = (const float*)d_in[5];
    const float* bout = (const float*)d_in[6];
    float* out = (float*)d_out;

    // workspace carve: 6 inverses + 3 ping-pong V buffers (~102 MB total)
    float* Minv = (float*)d_ws;
    float* bufA = Minv + (size_t)NLAYERS*NU*NU;
    float* bufB = bufA + (size_t)NBATCH*NU;
    float* bufC = bufB + (size_t)NBATCH*NU;

    const dim3 ggrid(NBATCH/BM, NU/BN);   // 256 x 2 = 512 blocks

    in_gemm<<<ggrid, 256, 0, stream>>>(x, Win, bin, bufA, bufB);       // V0=H, V1=tanh(H)
    invert_kernel<<<NLAYERS, 1024, 0, stream>>>(B0, Minv);

    float* v0 = bufA; float* v1 = bufB; float* fr = bufC;
    for (int l = 0; l < NLAYERS; ++l) {
        const float* Ml = Minv + (size_t)l*NU*NU;
        const float* ql = q + (size_t)l*NU;
        gemm_nn_neg<<<ggrid, 256, 0, stream>>>(v1, Ml, fr);      // newV0 = -V1 @ M   (into free buf)
        gemm_nt_q <<<ggrid, 256, 0, stream>>>(v0, Ml, ql, v1);   // newV1 = (V0+q) @ M^T (over old V1)
        float* tswap = v0; v0 = fr; fr = tswap;                  // old V0 becomes free
    }
    out_gemm<<<NBATCH/4, 256, 0, stream>>>(v0, Wout, bout, out);
}